// Round 1
// baseline (265.457 us; speedup 1.0000x reference)
//
#include <hip/hip_runtime.h>
#include <hip/hip_bf16.h>
#include <stdint.h>

#define B_ 2
#define N_ 2048
#define H_ 16
#define DH_ 64
#define DIM_ 1024
#define NH3 3072
#define ROWS (B_*N_)   // 4096

typedef __attribute__((ext_vector_type(8))) short bf16x8;
typedef __attribute__((ext_vector_type(4))) float f32x4;
typedef unsigned short u16;

__device__ __forceinline__ u16 f2bf(float f){
  union { float f; uint32_t u; } v; v.f = f;
  return (u16)((v.u + 0x7fffu + ((v.u >> 16) & 1u)) >> 16);
}

#define GLL16(g, l) __builtin_amdgcn_global_load_lds( \
    (const __attribute__((address_space(1))) void*)(g), \
    (__attribute__((address_space(3))) void*)(l), 16, 0, 0)

// ---------------- positions (cumsum of modality membership) ----------------
__global__ void k_pos(const int* __restrict__ mods, float* __restrict__ pos){
  const int b = blockIdx.x;
  const int lane = threadIdx.x;
  int off[4], len[4];
#pragma unroll
  for (int m = 0; m < 4; ++m){
    off[m] = mods[(b*4 + m)*3 + 1];
    len[m] = mods[(b*4 + m)*3 + 2];
  }
  int run = 0;
  for (int c = 0; c < N_/64; ++c){
    int n = c*64 + lane;
    int v = 0;
#pragma unroll
    for (int m = 0; m < 4; ++m)
      if (n >= off[m] + 1 && n < off[m] + len[m]) v = 1;
    int s = v;
#pragma unroll
    for (int d = 1; d < 64; d <<= 1){
      int t = __shfl_up(s, d);
      if (lane >= d) s += t;
    }
    pos[b*N_ + n] = (float)(n - (run + s));
    run += __shfl(s, 63);
  }
}

// ---------------- RoPE cos/sin tables ----------------
__global__ void k_ropetab(const float* __restrict__ pos, float* __restrict__ cosT, float* __restrict__ sinT){
  int t = blockIdx.x*256 + threadIdx.x;
  if (t >= B_*N_*32) return;
  int f = t & 31, bn = t >> 5;
  float inv = powf(10000.0f, -(float)(2*f) / 64.0f);
  float ang = pos[bn] * inv;
  float s, c;
  sincosf(ang, &s, &c);
  cosT[t] = c; sinT[t] = s;
}

// ---------------- fp32 -> bf16 transpose (weights) ----------------
__global__ void k_transpose(const float* __restrict__ src, u16* __restrict__ dst, int R, int C){
  __shared__ float tile[32][33];
  int tx = threadIdx.x & 31, ty = threadIdx.x >> 5; // 32x8
  int bc = blockIdx.x * 32, br = blockIdx.y * 32;
#pragma unroll
  for (int i = 0; i < 32; i += 8)
    tile[ty + i][tx] = src[(size_t)(br + ty + i)*C + bc + tx];
  __syncthreads();
#pragma unroll
  for (int i = 0; i < 32; i += 8)
    dst[(size_t)(bc + ty + i)*R + br + tx] = f2bf(tile[tx][ty + i]);
}

// ---------------- row-norm (x / ||x|| * sqrt(d) * (gamma+1)) ----------------
__global__ __launch_bounds__(256) void k_rmsnorm(const float* __restrict__ x, const float* __restrict__ gamma, u16* __restrict__ xn){
  int row = blockIdx.x, t = threadIdx.x;
  const float4 xv = ((const float4*)(x + (size_t)row*DIM_))[t];
  float ss = xv.x*xv.x + xv.y*xv.y + xv.z*xv.z + xv.w*xv.w;
#pragma unroll
  for (int d = 1; d < 64; d <<= 1) ss += __shfl_xor(ss, d);
  __shared__ float red[4];
  if ((t & 63) == 0) red[t >> 6] = ss;
  __syncthreads();
  float tot = red[0] + red[1] + red[2] + red[3];
  float scl = 32.0f / fmaxf(sqrtf(tot), 1e-12f);   // sqrt(1024)=32
  const float4 gv = ((const float4*)gamma)[t];
  ushort4 o;
  o.x = f2bf(xv.x * scl * (gv.x + 1.0f));
  o.y = f2bf(xv.y * scl * (gv.y + 1.0f));
  o.z = f2bf(xv.z * scl * (gv.z + 1.0f));
  o.w = f2bf(xv.w * scl * (gv.w + 1.0f));
  ((ushort4*)(xn + (size_t)row*DIM_))[t] = o;
}

// ---------------- 128x128 bf16 MFMA GEMM: C = A @ Bt^T ----------------
// A [M][K] bf16 row-major, Bt [N][K] bf16 row-major.
// MODE 0: epilogue scatters qkv -> qraw/kraw fp32 [B,H,N,64], vt bf16 [B,H,64,N]
// MODE 1: plain fp32 store to outf [M][Nc]
template<int MODE>
__global__ __launch_bounds__(256) void k_gemm(
    const u16* __restrict__ A, const u16* __restrict__ Bt,
    int K, int Nc,
    float* __restrict__ outf,
    float* __restrict__ qraw, float* __restrict__ kraw, u16* __restrict__ vt)
{
  __shared__ u16 lA[128*64];
  __shared__ u16 lB[128*64];
  const int tid = threadIdx.x;
  const int wid = tid >> 6, lane = tid & 63;
  const int m0 = blockIdx.x * 128, n0 = blockIdx.y * 128;
  const int wm = wid >> 1, wn = wid & 1;
  const int srow = lane >> 3, sch = lane & 7;
  const int r16 = lane & 15, g4 = lane >> 4;
  f32x4 acc[4][4] = {};
  const int ksteps = K >> 6;
  for (int kt = 0; kt < ksteps; ++kt){
    const int kb = kt*64;
#pragma unroll
    for (int i = 0; i < 4; ++i){
      const int reg = wid*4 + i;         // 16 regions of 8 rows (1KB each)
      const int row = reg*8 + srow;
      const int gch = sch ^ srow;        // pre-swizzled global source chunk
      GLL16(A  + (size_t)(m0 + row)*K + kb + gch*8, &lA[reg*512]);
      GLL16(Bt + (size_t)(n0 + row)*K + kb + gch*8, &lB[reg*512]);
    }
    __syncthreads();
#pragma unroll
    for (int t = 0; t < 2; ++t){
      bf16x8 af[4], bfr[4];
#pragma unroll
      for (int m = 0; m < 4; ++m){
        int row = wm*64 + m*16 + r16;
        int ch = (t*4 + g4) ^ (r16 & 7);
        af[m] = *(const bf16x8*)&lA[row*64 + ch*8];
      }
#pragma unroll
      for (int n = 0; n < 4; ++n){
        int row = wn*64 + n*16 + r16;
        int ch = (t*4 + g4) ^ (r16 & 7);
        bfr[n] = *(const bf16x8*)&lB[row*64 + ch*8];
      }
#pragma unroll
      for (int m = 0; m < 4; ++m)
#pragma unroll
        for (int n = 0; n < 4; ++n)
          acc[m][n] = __builtin_amdgcn_mfma_f32_16x16x32_bf16(af[m], bfr[n], acc[m][n], 0, 0, 0);
    }
    __syncthreads();
  }
#pragma unroll
  for (int m = 0; m < 4; ++m){
#pragma unroll
    for (int n = 0; n < 4; ++n){
#pragma unroll
      for (int r = 0; r < 4; ++r){
        const int grow = m0 + wm*64 + m*16 + g4*4 + r;
        const int gcol = n0 + wn*64 + n*16 + r16;
        const float v = acc[m][n][r];
        if constexpr (MODE == 0){
          const int b = grow >> 11, nn = grow & (N_-1);
          const int s3 = gcol >> 10, hh = (gcol >> 6) & 15, d = gcol & 63;
          const size_t hb = (size_t)(b*H_ + hh);
          if (s3 == 0)      qraw[(hb*N_ + nn)*64 + d] = v;
          else if (s3 == 1) kraw[(hb*N_ + nn)*64 + d] = v;
          else              vt[(hb*64 + d)*N_ + nn] = f2bf(v);
        } else {
          outf[(size_t)grow*Nc + gcol] = v;
        }
      }
    }
  }
}

// ---------------- RoPE apply: fp32 raw -> bf16 [B,H,N,64] ----------------
__global__ void k_rope(const float* __restrict__ qraw, const float* __restrict__ kraw,
                       const float* __restrict__ cosT, const float* __restrict__ sinT,
                       u16* __restrict__ qb, u16* __restrict__ kb){
  int t = blockIdx.x*256 + threadIdx.x;
  if (t >= B_*H_*N_*8) return;
  int q8 = t & 7, row = t >> 3;
  int n = row & (N_-1), bh = row >> 11, b = bh >> 4;
  const float* src = (blockIdx.y ? kraw : qraw) + (size_t)row*64 + q8*8;
  u16* dst = (blockIdx.y ? kb : qb) + (size_t)row*64 + q8*8;
  const float* ct = cosT + (size_t)(b*N_ + n)*32 + q8*4;
  const float* st = sinT + (size_t)(b*N_ + n)*32 + q8*4;
  float4 a0 = ((const float4*)src)[0];
  float4 a1 = ((const float4*)src)[1];
  float xx[8] = {a0.x, a0.y, a0.z, a0.w, a1.x, a1.y, a1.z, a1.w};
  u16 o[8];
#pragma unroll
  for (int p = 0; p < 4; ++p){
    float cc = ct[p], ssn = st[p];
    float e0 = xx[2*p], e1 = xx[2*p+1];
    o[2*p]   = f2bf(e0*cc - e1*ssn);
    o[2*p+1] = f2bf(e1*cc + e0*ssn);
  }
  ushort4* d4 = (ushort4*)dst;
  d4[0] = make_ushort4(o[0],o[1],o[2],o[3]);
  d4[1] = make_ushort4(o[4],o[5],o[6],o[7]);
}

// ---------------- fused attention (flash-style, tile-skip, softcap) ----------------
__global__ __launch_bounds__(256) void k_attn(
    const u16* __restrict__ qb, const u16* __restrict__ kb, const u16* __restrict__ vt,
    const int* __restrict__ mods, u16* __restrict__ xo)
{
  __shared__ u16 lK[64*64];
  __shared__ u16 lV[64*64];
  __shared__ u16 lP[4*16*64];
  const int tid = threadIdx.x, wid = tid >> 6, lane = tid & 63;
  const int qt = blockIdx.x, bh = blockIdx.y;
  const int b = bh >> 4, h = bh & 15;
  const int r16 = lane & 15, g4 = lane >> 4;
  const int srow = lane >> 3, sch = lane & 7;
  int moff[4], mend[4];
#pragma unroll
  for (int m = 0; m < 4; ++m){
    moff[m] = mods[(b*4+m)*3+1];
    mend[m] = moff[m] + mods[(b*4+m)*3+2];
  }
  const int q0 = qt*64 + wid*16;
  const int imax = qt*64 + 63;
  const u16* qrow = qb + ((size_t)bh*N_ + q0 + r16)*64;
  bf16x8 aq[2];
  aq[0] = *(const bf16x8*)&qrow[g4*8];
  aq[1] = *(const bf16x8*)&qrow[32 + g4*8];

  float mrun[4] = {-1e30f,-1e30f,-1e30f,-1e30f};
  float lrun[4] = {0.f,0.f,0.f,0.f};
  f32x4 o[4] = {};
  u16* lPw = &lP[wid*1024];
  const u16* kbase = kb + (size_t)bh*N_*64;
  const u16* vbase = vt + (size_t)bh*64*N_;

  for (int kt = 0; kt < N_/64; ++kt){
    bool proc = (kt*64 <= imax);
    if (!proc){
#pragma unroll
      for (int m = 0; m < 4; ++m)
        if (imax >= moff[m] && kt*64 < mend[m]) proc = true;
    }
    if (!proc) continue;               // block-uniform skip
    __syncthreads();                   // protect lK/lV from previous iter readers
#pragma unroll
    for (int i = 0; i < 2; ++i){
      int reg = wid*2 + i;             // 8 regions each for K and V
      int row = reg*8 + srow;
      int gch = sch ^ srow;
      GLL16(kbase + (size_t)(kt*64 + row)*64 + gch*8, &lK[reg*512]);
      GLL16(vbase + (size_t)row*N_ + kt*64 + gch*8,   &lV[reg*512]);
    }
    __syncthreads();
    // S = Q @ K^T  (16 q-rows x 64 k-cols per wave)
    f32x4 s[4] = {};
#pragma unroll
    for (int cb = 0; cb < 4; ++cb){
#pragma unroll
      for (int t = 0; t < 2; ++t){
        int row = cb*16 + r16;
        int ch = (t*4 + g4) ^ (row & 7);
        bf16x8 bk = *(const bf16x8*)&lK[row*64 + ch*8];
        s[cb] = __builtin_amdgcn_mfma_f32_16x16x32_bf16(aq[t], bk, s[cb], 0, 0, 0);
      }
    }
    // softcap + mask + online softmax
    float rmax[4] = {-1e30f,-1e30f,-1e30f,-1e30f};
#pragma unroll
    for (int cb = 0; cb < 4; ++cb){
#pragma unroll
      for (int r = 0; r < 4; ++r){
        float v = s[cb][r] * 0.125f;                 // dh^-0.5
        float e = __expf(v * (2.0f/50.0f));
        float th = 50.0f * (e - 1.0f) / (e + 1.0f);  // 50*tanh(v/50)
        int i = q0 + g4*4 + r;
        int j = kt*64 + cb*16 + r16;
        bool keep = (j <= i);
        if (!keep){
#pragma unroll
          for (int m = 0; m < 4; ++m)
            keep = keep || ((i >= moff[m]) && (j < mend[m]));
        }
        v = keep ? th : -1e30f;
        s[cb][r] = v;
        rmax[r] = fmaxf(rmax[r], v);
      }
    }
#pragma unroll
    for (int r = 0; r < 4; ++r){
#pragma unroll
      for (int d = 1; d < 16; d <<= 1)
        rmax[r] = fmaxf(rmax[r], __shfl_xor(rmax[r], d));
    }
    float alpha[4], rsum[4];
#pragma unroll
    for (int r = 0; r < 4; ++r){
      float mn = fmaxf(mrun[r], rmax[r]);
      alpha[r] = __expf(mrun[r] - mn);
      mrun[r] = mn;
      rsum[r] = 0.f;
    }
#pragma unroll
    for (int cb = 0; cb < 4; ++cb){
#pragma unroll
      for (int r = 0; r < 4; ++r){
        float p = __expf(s[cb][r] - mrun[r]);
        s[cb][r] = p;
        rsum[r] += p;
      }
    }
#pragma unroll
    for (int r = 0; r < 4; ++r){
#pragma unroll
      for (int d = 1; d < 16; d <<= 1)
        rsum[r] += __shfl_xor(rsum[r], d);
      lrun[r] = lrun[r]*alpha[r] + rsum[r];
    }
#pragma unroll
    for (int cb = 0; cb < 4; ++cb){
#pragma unroll
      for (int r = 0; r < 4; ++r)
        o[cb][r] *= alpha[r];
    }
    // P -> per-wave LDS (bf16, swizzled), then read back as MFMA A-frags
#pragma unroll
    for (int cb = 0; cb < 4; ++cb){
#pragma unroll
      for (int r = 0; r < 4; ++r){
        int row = g4*4 + r;
        int col = cb*16 + r16;
        int ch = (col >> 3) ^ (row & 7);
        lPw[row*64 + ch*8 + (col & 7)] = f2bf(s[cb][r]);
      }
    }
    asm volatile("s_waitcnt lgkmcnt(0)" ::: "memory");
    bf16x8 ap[2];
#pragma unroll
    for (int t = 0; t < 2; ++t){
      int ch = (t*4 + g4) ^ (r16 & 7);
      ap[t] = *(const bf16x8*)&lPw[r16*64 + ch*8];
    }
#pragma unroll
    for (int cb = 0; cb < 4; ++cb){
#pragma unroll
      for (int t = 0; t < 2; ++t){
        int d = cb*16 + r16;
        int ch = (t*4 + g4) ^ (d & 7);
        bf16x8 bv = *(const bf16x8*)&lV[d*64 + ch*8];
        o[cb] = __builtin_amdgcn_mfma_f32_16x16x32_bf16(ap[t], bv, o[cb], 0, 0, 0);
      }
    }
  }
  // epilogue: O / l  -> xo [b,n,h*64+d] bf16
#pragma unroll
  for (int r = 0; r < 4; ++r){
    float linv = 1.0f / lrun[r];
#pragma unroll
    for (int cb = 0; cb < 4; ++cb){
      int i = q0 + g4*4 + r;
      xo[(size_t)(b*N_ + i)*DIM_ + h*64 + cb*16 + r16] = f2bf(o[cb][r]*linv);
    }
  }
}

extern "C" void kernel_launch(void* const* d_in, const int* in_sizes, int n_in,
                              void* d_out, int out_size, void* d_ws, size_t ws_size,
                              hipStream_t stream){
  const float* x     = (const float*)d_in[0];
  const int*   mods  = (const int*)d_in[1];
  const float* gamma = (const float*)d_in[2];
  const float* wqkv  = (const float*)d_in[3];
  const float* wout  = (const float*)d_in[4];
  float* outp = (float*)d_out;

  char* p = (char*)d_ws;
  auto alloc = [&](size_t bytes) -> char* {
    char* r = p; p += (bytes + 255) & ~(size_t)255; return r;
  };
  float* pos   = (float*)alloc((size_t)B_*N_*4);
  float* cosT  = (float*)alloc((size_t)B_*N_*32*4);
  float* sinT  = (float*)alloc((size_t)B_*N_*32*4);
  u16* wqkvT   = (u16*)alloc((size_t)NH3*DIM_*2);
  u16* woutT   = (u16*)alloc((size_t)DIM_*DIM_*2);
  u16* xn      = (u16*)alloc((size_t)ROWS*DIM_*2);
  float* qraw  = (float*)alloc((size_t)B_*H_*N_*64*4);
  float* kraw  = (float*)alloc((size_t)B_*H_*N_*64*4);
  u16* qbb     = (u16*)alloc((size_t)B_*H_*N_*64*2);
  u16* kbb     = (u16*)alloc((size_t)B_*H_*N_*64*2);
  u16* vtb     = (u16*)alloc((size_t)B_*H_*N_*64*2);
  u16* xo      = (u16*)alloc((size_t)ROWS*DIM_*2);

  k_pos<<<B_, 64, 0, stream>>>(mods, pos);
  k_ropetab<<<(B_*N_*32 + 255)/256, 256, 0, stream>>>(pos, cosT, sinT);
  k_transpose<<<dim3(NH3/32, DIM_/32), 256, 0, stream>>>(wqkv, wqkvT, DIM_, NH3);
  k_transpose<<<dim3(DIM_/32, DIM_/32), 256, 0, stream>>>(wout, woutT, DIM_, DIM_);
  k_rmsnorm<<<ROWS, 256, 0, stream>>>(x, gamma, xn);
  k_gemm<0><<<dim3(ROWS/128, NH3/128), 256, 0, stream>>>(xn, wqkvT, DIM_, NH3, nullptr, qraw, kraw, vtb);
  k_rope<<<dim3((B_*H_*N_*8)/256, 2), 256, 0, stream>>>(qraw, kraw, cosT, sinT, qbb, kbb);
  k_attn<<<dim3(N_/64, B_*H_), 256, 0, stream>>>(qbb, kbb, vtb, mods, xo);
  k_gemm<1><<<dim3(ROWS/128, DIM_/128), 256, 0, stream>>>(xo, woutT, DIM_, DIM_, outp, nullptr, nullptr, nullptr);
}

// Round 2
// 172.578 us; speedup vs baseline: 1.5382x; 1.5382x over previous
//
#include <hip/hip_runtime.h>
#include <hip/hip_bf16.h>
#include <stdint.h>

#define B_ 2
#define N_ 2048
#define H_ 16
#define DIM_ 1024
#define NH3 3072
#define ROWS (B_*N_)   // 4096

typedef __attribute__((ext_vector_type(8))) short bf16x8;
typedef __attribute__((ext_vector_type(4))) float f32x4;
typedef unsigned short u16;

__device__ __forceinline__ u16 f2bf(float f){
  union { float f; uint32_t u; } v; v.f = f;
  return (u16)((v.u + 0x7fffu + ((v.u >> 16) & 1u)) >> 16);
}

#if __has_builtin(__builtin_amdgcn_exp2f)
#define EXP2F(x) __builtin_amdgcn_exp2f(x)
#else
#define EXP2F(x) __expf((x) * 0.6931471805599453f)
#endif
#if __has_builtin(__builtin_amdgcn_rcpf)
#define RCPF(x) __builtin_amdgcn_rcpf(x)
#else
#define RCPF(x) (1.0f / (x))
#endif

#define GLL16(g, l) __builtin_amdgcn_global_load_lds( \
    (const __attribute__((address_space(1))) void*)(g), \
    (__attribute__((address_space(3))) void*)(l), 16, 0, 0)

// ---------------- positions + mask thresholds ----------------
__global__ void k_pos(const int* __restrict__ mods, float* __restrict__ pos,
                      int* __restrict__ thrg){
  const int b = blockIdx.x;
  const int lane = threadIdx.x;
  int off[4], len[4];
#pragma unroll
  for (int m = 0; m < 4; ++m){
    off[m] = mods[(b*4 + m)*3 + 1];
    len[m] = mods[(b*4 + m)*3 + 2];
  }
  int run = 0;
  for (int c = 0; c < N_/64; ++c){
    int n = c*64 + lane;
    int v = 0;
#pragma unroll
    for (int m = 0; m < 4; ++m)
      if (n >= off[m] + 1 && n < off[m] + len[m]) v = 1;
    int s = v;
#pragma unroll
    for (int d = 1; d < 64; d <<= 1){
      int t = __shfl_up(s, d);
      if (lane >= d) s += t;
    }
    pos[b*N_ + n] = (float)(n - (run + s));
    run += __shfl(s, 63);
    // mask threshold: keep(i,j) <=> i >= thr[j]
    int th = n;
#pragma unroll
    for (int m = 0; m < 4; ++m)
      if (n < off[m] + len[m]) th = min(th, off[m]);
    thrg[b*N_ + n] = th;
  }
}

// ---------------- RoPE cos/sin tables ----------------
__global__ void k_ropetab(const float* __restrict__ pos, float* __restrict__ cosT, float* __restrict__ sinT){
  int t = blockIdx.x*256 + threadIdx.x;
  if (t >= B_*N_*32) return;
  int f = t & 31, bn = t >> 5;
  float inv = powf(10000.0f, -(float)(2*f) / 64.0f);
  float ang = pos[bn] * inv;
  float s, c;
  sincosf(ang, &s, &c);
  cosT[t] = c; sinT[t] = s;
}

// ---------------- fp32 -> bf16 transpose (weights) ----------------
__global__ void k_transpose(const float* __restrict__ src, u16* __restrict__ dst, int R, int C){
  __shared__ float tile[32][33];
  int tx = threadIdx.x & 31, ty = threadIdx.x >> 5; // 32x8
  int bc = blockIdx.x * 32, br = blockIdx.y * 32;
#pragma unroll
  for (int i = 0; i < 32; i += 8)
    tile[ty + i][tx] = src[(size_t)(br + ty + i)*C + bc + tx];
  __syncthreads();
#pragma unroll
  for (int i = 0; i < 32; i += 8)
    dst[(size_t)(bc + ty + i)*R + br + tx] = f2bf(tile[tx][ty + i]);
}

// ---------------- row-norm (x / ||x|| * sqrt(d) * (gamma+1)) ----------------
__global__ __launch_bounds__(256) void k_rmsnorm(const float* __restrict__ x, const float* __restrict__ gamma, u16* __restrict__ xn){
  int row = blockIdx.x, t = threadIdx.x;
  const float4 xv = ((const float4*)(x + (size_t)row*DIM_))[t];
  float ss = xv.x*xv.x + xv.y*xv.y + xv.z*xv.z + xv.w*xv.w;
#pragma unroll
  for (int d = 1; d < 64; d <<= 1) ss += __shfl_xor(ss, d);
  __shared__ float red[4];
  if ((t & 63) == 0) red[t >> 6] = ss;
  __syncthreads();
  float tot = red[0] + red[1] + red[2] + red[3];
  float scl = 32.0f / fmaxf(sqrtf(tot), 1e-12f);   // sqrt(1024)=32
  const float4 gv = ((const float4*)gamma)[t];
  ushort4 o;
  o.x = f2bf(xv.x * scl * (gv.x + 1.0f));
  o.y = f2bf(xv.y * scl * (gv.y + 1.0f));
  o.z = f2bf(xv.z * scl * (gv.z + 1.0f));
  o.w = f2bf(xv.w * scl * (gv.w + 1.0f));
  ((ushort4*)(xn + (size_t)row*DIM_))[t] = o;
}

// ---------------- 128x128 bf16 MFMA GEMM: C = A @ Bt^T ----------------
// MODE 0: epilogue applies RoPE to q/k and stores bf16 q/k [B,H,N,64], v^T bf16 [B,H,64,N]
// MODE 1: plain fp32 store to outf [M][Nc]
template<int MODE>
__global__ __launch_bounds__(256) void k_gemm(
    const u16* __restrict__ A, const u16* __restrict__ Bt,
    int K, int Nc,
    float* __restrict__ outf,
    const float* __restrict__ cosT, const float* __restrict__ sinT,
    u16* __restrict__ qo, u16* __restrict__ ko, u16* __restrict__ vt)
{
  __shared__ u16 lA[128*64];
  __shared__ u16 lB[128*64];
  const int tid = threadIdx.x;
  const int wid = tid >> 6, lane = tid & 63;
  const int m0 = blockIdx.x * 128, n0 = blockIdx.y * 128;
  const int wm = wid >> 1, wn = wid & 1;
  const int srow = lane >> 3, sch = lane & 7;
  const int r16 = lane & 15, g4 = lane >> 4;
  f32x4 acc[4][4] = {};
  const int ksteps = K >> 6;
  for (int kt = 0; kt < ksteps; ++kt){
    const int kb = kt*64;
#pragma unroll
    for (int i = 0; i < 4; ++i){
      const int reg = wid*4 + i;         // 16 regions of 8 rows (1KB each)
      const int row = reg*8 + srow;
      const int gch = sch ^ srow;        // pre-swizzled global source chunk
      GLL16(A  + (size_t)(m0 + row)*K + kb + gch*8, &lA[reg*512]);
      GLL16(Bt + (size_t)(n0 + row)*K + kb + gch*8, &lB[reg*512]);
    }
    __syncthreads();
#pragma unroll
    for (int t = 0; t < 2; ++t){
      bf16x8 af[4], bfr[4];
#pragma unroll
      for (int m = 0; m < 4; ++m){
        int row = wm*64 + m*16 + r16;
        int ch = (t*4 + g4) ^ (r16 & 7);
        af[m] = *(const bf16x8*)&lA[row*64 + ch*8];
      }
#pragma unroll
      for (int n = 0; n < 4; ++n){
        int row = wn*64 + n*16 + r16;
        int ch = (t*4 + g4) ^ (r16 & 7);
        bfr[n] = *(const bf16x8*)&lB[row*64 + ch*8];
      }
#pragma unroll
      for (int m = 0; m < 4; ++m)
#pragma unroll
        for (int n = 0; n < 4; ++n)
          acc[m][n] = __builtin_amdgcn_mfma_f32_16x16x32_bf16(af[m], bfr[n], acc[m][n], 0, 0, 0);
    }
    __syncthreads();
  }
#pragma unroll
  for (int m = 0; m < 4; ++m){
#pragma unroll
    for (int n = 0; n < 4; ++n){
#pragma unroll
      for (int r = 0; r < 4; ++r){
        const int grow = m0 + wm*64 + m*16 + g4*4 + r;
        const int gcol = n0 + wn*64 + n*16 + r16;
        const float v = acc[m][n][r];
        if constexpr (MODE == 0){
          const float part = __shfl_xor(v, 1);   // RoPE partner (d^1)
          const int b = grow >> 11, nn = grow & (N_-1);
          const int s3 = gcol >> 10, hh = (gcol >> 6) & 15, d = gcol & 63;
          const size_t hb = (size_t)(b*H_ + hh);
          if (s3 == 2){
            vt[(hb*64 + d)*N_ + nn] = f2bf(v);
          } else {
            const int pidx = (b*N_ + nn)*32 + (d >> 1);
            const float c = cosT[pidx], sn = sinT[pidx];
            const float rot = (d & 1) ? (v*c + part*sn) : (v*c - part*sn);
            const u16 val = f2bf(rot);
            if (s3 == 0) qo[(hb*N_ + nn)*64 + d] = val;
            else         ko[(hb*N_ + nn)*64 + d] = val;
          }
        } else {
          outf[(size_t)grow*Nc + gcol] = v;
        }
      }
    }
  }
}

// ---------------- fused attention (flash-style, fixed-max softcap softmax) ----------------
__global__ __launch_bounds__(256) void k_attn(
    const u16* __restrict__ qb, const u16* __restrict__ kb, const u16* __restrict__ vt,
    const int* __restrict__ mods, const int* __restrict__ thrg, u16* __restrict__ xo)
{
  __shared__ u16 lK[64*64];
  __shared__ u16 lV[64*64];
  __shared__ u16 lP[4*16*72];       // per-wave 16x64 P, padded stride 72
  const int tid = threadIdx.x, wid = tid >> 6, lane = tid & 63;
  const int bh = blockIdx.y;
  const int b = bh >> 4, h = bh & 15;
  const int r16 = lane & 15, g4 = lane >> 4;
  const int srow = lane >> 3, sch = lane & 7;
  int moff[4], mend[4];
#pragma unroll
  for (int m = 0; m < 4; ++m){
    moff[m] = mods[(b*4+m)*3+1];
    mend[m] = moff[m] + mods[(b*4+m)*3+2];
  }
  const int* thr_b = thrg + b*N_;
  const u16* kbase = kb + (size_t)bh*N_*64;
  const u16* vbase = vt + (size_t)bh*64*N_;
  u16* lPw = &lP[wid*16*72];

  for (int pass = 0; pass < 2; ++pass){
    const int qt = pass ? (31 - (int)blockIdx.x) : (int)blockIdx.x;  // triangle pairing
    const int q0 = qt*64 + wid*16;
    const int imax = qt*64 + 63;
    const u16* qrow = qb + ((size_t)bh*N_ + q0 + r16)*64;
    const bf16x8 aq0 = *(const bf16x8*)&qrow[g4*8];
    const bf16x8 aq1 = *(const bf16x8*)&qrow[32 + g4*8];
    float lsum[4] = {0.f, 0.f, 0.f, 0.f};
    f32x4 o[4] = {};

    for (int kt = 0; kt < N_/64; ++kt){
      bool proc = (kt*64 <= imax);
      if (!proc){
#pragma unroll
        for (int m = 0; m < 4; ++m)
          if (imax >= moff[m] && kt*64 < mend[m]) proc = true;
      }
      if (!proc) continue;             // block-uniform skip
      __syncthreads();                 // previous-iter readers done
#pragma unroll
      for (int i = 0; i < 2; ++i){
        int reg = wid*2 + i;
        int row = reg*8 + srow;
        int gch = sch ^ srow;
        GLL16(kbase + (size_t)(kt*64 + row)*64 + gch*8, &lK[reg*512]);
        GLL16(vbase + (size_t)row*N_ + kt*64 + gch*8,   &lV[reg*512]);
      }
      __syncthreads();
      int tj[4];
#pragma unroll
      for (int cb = 0; cb < 4; ++cb)
        tj[cb] = thr_b[kt*64 + cb*16 + r16];
      // S = Q @ K^T
      f32x4 s[4] = {};
#pragma unroll
      for (int cb = 0; cb < 4; ++cb){
#pragma unroll
        for (int t = 0; t < 2; ++t){
          int row = cb*16 + r16;
          int ch = (t*4 + g4) ^ (row & 7);
          bf16x8 bk = *(const bf16x8*)&lK[row*64 + ch*8];
          s[cb] = __builtin_amdgcn_mfma_f32_16x16x32_bf16(t ? aq1 : aq0, bk, s[cb], 0, 0, 0);
        }
      }
      // softcap -> p = exp(50*tanh(s*0.125/50)) (fixed max, no rescale), mask, bf16 to LDS
#pragma unroll
      for (int cb = 0; cb < 4; ++cb){
#pragma unroll
        for (int r = 0; r < 4; ++r){
          const float e = EXP2F(s[cb][r] * 0.0072134752f);         // 2^(s*0.005*log2e)
          const float w = RCPF(e + 1.0f);
          float p = EXP2F(fmaf(w, -144.2695041f, 72.13475205f));   // exp(50-100w)
          const int i = q0 + g4*4 + r;
          p = (i >= tj[cb]) ? p : 0.0f;
          lsum[r] += p;
          union { float f; uint32_t u; } cv; cv.f = p;
          lPw[(g4*4 + r)*72 + cb*16 + r16] = (u16)((cv.u + 0x8000u) >> 16);  // RNA bf16
        }
      }
      asm volatile("s_waitcnt lgkmcnt(0)" ::: "memory");
      const bf16x8 ap0 = *(const bf16x8*)&lPw[r16*72 + g4*8];
      const bf16x8 ap1 = *(const bf16x8*)&lPw[r16*72 + 32 + g4*8];
#pragma unroll
      for (int cb = 0; cb < 4; ++cb){
#pragma unroll
        for (int t = 0; t < 2; ++t){
          int d = cb*16 + r16;
          int ch = (t*4 + g4) ^ (d & 7);
          bf16x8 bv = *(const bf16x8*)&lV[d*64 + ch*8];
          o[cb] = __builtin_amdgcn_mfma_f32_16x16x32_bf16(t ? ap1 : ap0, bv, o[cb], 0, 0, 0);
        }
      }
    }
    // final sum reduce across the 16 col-lanes, then normalize + store
#pragma unroll
    for (int r = 0; r < 4; ++r){
#pragma unroll
      for (int d = 1; d < 16; d <<= 1)
        lsum[r] += __shfl_xor(lsum[r], d);
    }
#pragma unroll
    for (int r = 0; r < 4; ++r){
      const float linv = RCPF(lsum[r]);
      const int i = q0 + g4*4 + r;
#pragma unroll
      for (int cb = 0; cb < 4; ++cb)
        xo[(size_t)(b*N_ + i)*DIM_ + h*64 + cb*16 + r16] = f2bf(o[cb][r]*linv);
    }
  }
}

extern "C" void kernel_launch(void* const* d_in, const int* in_sizes, int n_in,
                              void* d_out, int out_size, void* d_ws, size_t ws_size,
                              hipStream_t stream){
  const float* x     = (const float*)d_in[0];
  const int*   mods  = (const int*)d_in[1];
  const float* gamma = (const float*)d_in[2];
  const float* wqkv  = (const float*)d_in[3];
  const float* wout  = (const float*)d_in[4];
  float* outp = (float*)d_out;

  char* p = (char*)d_ws;
  auto alloc = [&](size_t bytes) -> char* {
    char* r = p; p += (bytes + 255) & ~(size_t)255; return r;
  };
  float* pos   = (float*)alloc((size_t)B_*N_*4);
  int*   thrg  = (int*)alloc((size_t)B_*N_*4);
  float* cosT  = (float*)alloc((size_t)B_*N_*32*4);
  float* sinT  = (float*)alloc((size_t)B_*N_*32*4);
  u16* wqkvT   = (u16*)alloc((size_t)NH3*DIM_*2);
  u16* woutT   = (u16*)alloc((size_t)DIM_*DIM_*2);
  u16* xn      = (u16*)alloc((size_t)ROWS*DIM_*2);
  u16* qbb     = (u16*)alloc((size_t)B_*H_*N_*64*2);
  u16* kbb     = (u16*)alloc((size_t)B_*H_*N_*64*2);
  u16* vtb     = (u16*)alloc((size_t)B_*H_*N_*64*2);
  u16* xo      = (u16*)alloc((size_t)ROWS*DIM_*2);

  k_pos<<<B_, 64, 0, stream>>>(mods, pos, thrg);
  k_ropetab<<<(B_*N_*32 + 255)/256, 256, 0, stream>>>(pos, cosT, sinT);
  k_transpose<<<dim3(NH3/32, DIM_/32), 256, 0, stream>>>(wqkv, wqkvT, DIM_, NH3);
  k_transpose<<<dim3(DIM_/32, DIM_/32), 256, 0, stream>>>(wout, woutT, DIM_, DIM_);
  k_rmsnorm<<<ROWS, 256, 0, stream>>>(x, gamma, xn);
  k_gemm<0><<<dim3(ROWS/128, NH3/128), 256, 0, stream>>>(xn, wqkvT, DIM_, NH3, nullptr, cosT, sinT, qbb, kbb, vtb);
  k_attn<<<dim3(16, B_*H_), 256, 0, stream>>>(qbb, kbb, vtb, mods, thrg, xo);
  k_gemm<1><<<dim3(ROWS/128, DIM_/128), 256, 0, stream>>>(xo, woutT, DIM_, DIM_, outp, nullptr, nullptr, nullptr, nullptr, nullptr);
}

// Round 3
// 170.043 us; speedup vs baseline: 1.5611x; 1.0149x over previous
//
#include <hip/hip_runtime.h>
#include <hip/hip_bf16.h>
#include <stdint.h>

#define B_ 2
#define N_ 2048
#define H_ 16
#define DIM_ 1024
#define NH3 3072
#define ROWS (B_*N_)   // 4096

typedef __attribute__((ext_vector_type(8))) short bf16x8;
typedef __attribute__((ext_vector_type(4))) float f32x4;
typedef unsigned short u16;

__device__ __forceinline__ u16 f2bf(float f){
  union { float f; uint32_t u; } v; v.f = f;
  return (u16)((v.u + 0x7fffu + ((v.u >> 16) & 1u)) >> 16);
}

#if __has_builtin(__builtin_amdgcn_exp2f)
#define EXP2F(x) __builtin_amdgcn_exp2f(x)
#else
#define EXP2F(x) __expf((x) * 0.6931471805599453f)
#endif
#if __has_builtin(__builtin_amdgcn_rcpf)
#define RCPF(x) __builtin_amdgcn_rcpf(x)
#else
#define RCPF(x) (1.0f / (x))
#endif

#define GLL16(g, l) __builtin_amdgcn_global_load_lds( \
    (const __attribute__((address_space(1))) void*)(g), \
    (__attribute__((address_space(3))) void*)(l), 16, 0, 0)

// ---------------- positions ----------------
__global__ void k_pos(const int* __restrict__ mods, float* __restrict__ pos){
  const int b = blockIdx.x;
  const int lane = threadIdx.x;
  int off[4], len[4];
#pragma unroll
  for (int m = 0; m < 4; ++m){
    off[m] = mods[(b*4 + m)*3 + 1];
    len[m] = mods[(b*4 + m)*3 + 2];
  }
  int run = 0;
  for (int c = 0; c < N_/64; ++c){
    int n = c*64 + lane;
    int v = 0;
#pragma unroll
    for (int m = 0; m < 4; ++m)
      if (n >= off[m] + 1 && n < off[m] + len[m]) v = 1;
    int s = v;
#pragma unroll
    for (int d = 1; d < 64; d <<= 1){
      int t = __shfl_up(s, d);
      if (lane >= d) s += t;
    }
    pos[b*N_ + n] = (float)(n - (run + s));
    run += __shfl(s, 63);
  }
}

// ---------------- RoPE cos/sin tables ----------------
__global__ void k_ropetab(const float* __restrict__ pos, float* __restrict__ cosT, float* __restrict__ sinT){
  int t = blockIdx.x*256 + threadIdx.x;
  if (t >= B_*N_*32) return;
  int f = t & 31, bn = t >> 5;
  float inv = powf(10000.0f, -(float)(2*f) / 64.0f);
  float ang = pos[bn] * inv;
  float s, c;
  sincosf(ang, &s, &c);
  cosT[t] = c; sinT[t] = s;
}

// ---------------- fp32 -> bf16 transpose (weights) ----------------
__global__ void k_transpose(const float* __restrict__ src, u16* __restrict__ dst, int R, int C){
  __shared__ float tile[32][33];
  int tx = threadIdx.x & 31, ty = threadIdx.x >> 5; // 32x8
  int bc = blockIdx.x * 32, br = blockIdx.y * 32;
#pragma unroll
  for (int i = 0; i < 32; i += 8)
    tile[ty + i][tx] = src[(size_t)(br + ty + i)*C + bc + tx];
  __syncthreads();
#pragma unroll
  for (int i = 0; i < 32; i += 8)
    dst[(size_t)(bc + ty + i)*R + br + tx] = f2bf(tile[tx][ty + i]);
}

// ---------------- row-norm (x / ||x|| * sqrt(d) * (gamma+1)) ----------------
__global__ __launch_bounds__(256) void k_rmsnorm(const float* __restrict__ x, const float* __restrict__ gamma, u16* __restrict__ xn){
  int row = blockIdx.x, t = threadIdx.x;
  const float4 xv = ((const float4*)(x + (size_t)row*DIM_))[t];
  float ss = xv.x*xv.x + xv.y*xv.y + xv.z*xv.z + xv.w*xv.w;
#pragma unroll
  for (int d = 1; d < 64; d <<= 1) ss += __shfl_xor(ss, d);
  __shared__ float red[4];
  if ((t & 63) == 0) red[t >> 6] = ss;
  __syncthreads();
  float tot = red[0] + red[1] + red[2] + red[3];
  float scl = 32.0f / fmaxf(sqrtf(tot), 1e-12f);   // sqrt(1024)=32
  const float4 gv = ((const float4*)gamma)[t];
  ushort4 o;
  o.x = f2bf(xv.x * scl * (gv.x + 1.0f));
  o.y = f2bf(xv.y * scl * (gv.y + 1.0f));
  o.z = f2bf(xv.z * scl * (gv.z + 1.0f));
  o.w = f2bf(xv.w * scl * (gv.w + 1.0f));
  ((ushort4*)(xn + (size_t)row*DIM_))[t] = o;
}

// ---------------- 128x128 bf16 MFMA GEMM: C = A @ Bt^T ----------------
// MODE 0: epilogue applies RoPE to q/k and stores bf16 q/k [B,H,N,64], v^T bf16 [B,H,64,N]
// MODE 1: plain fp32 store to outf [M][Nc]
template<int MODE>
__global__ __launch_bounds__(256) void k_gemm(
    const u16* __restrict__ A, const u16* __restrict__ Bt,
    int K, int Nc,
    float* __restrict__ outf,
    const float* __restrict__ cosT, const float* __restrict__ sinT,
    u16* __restrict__ qo, u16* __restrict__ ko, u16* __restrict__ vt)
{
  __shared__ u16 lA[128*64];
  __shared__ u16 lB[128*64];
  const int tid = threadIdx.x;
  const int wid = tid >> 6, lane = tid & 63;
  // XCD-aware bijective chunked remap (nwg % 8 == 0 for both launches)
  const int nx = gridDim.x;
  const int orig = blockIdx.y * nx + blockIdx.x;
  const int qq = (nx * gridDim.y) >> 3;
  const int wgid = (orig & 7) * qq + (orig >> 3);
  const int m0 = (wgid % nx) * 128, n0 = (wgid / nx) * 128;
  const int wm = wid >> 1, wn = wid & 1;
  const int srow = lane >> 3, sch = lane & 7;
  const int r16 = lane & 15, g4 = lane >> 4;
  f32x4 acc[4][4] = {};
  const int ksteps = K >> 6;
  for (int kt = 0; kt < ksteps; ++kt){
    const int kb = kt*64;
#pragma unroll
    for (int i = 0; i < 4; ++i){
      const int reg = wid*4 + i;         // 16 regions of 8 rows (1KB each)
      const int row = reg*8 + srow;
      const int gch = sch ^ srow;        // pre-swizzled global source chunk
      GLL16(A  + (size_t)(m0 + row)*K + kb + gch*8, &lA[reg*512]);
      GLL16(Bt + (size_t)(n0 + row)*K + kb + gch*8, &lB[reg*512]);
    }
    __syncthreads();
#pragma unroll
    for (int t = 0; t < 2; ++t){
      bf16x8 af[4], bfr[4];
#pragma unroll
      for (int m = 0; m < 4; ++m){
        int row = wm*64 + m*16 + r16;
        int ch = (t*4 + g4) ^ (r16 & 7);
        af[m] = *(const bf16x8*)&lA[row*64 + ch*8];
      }
#pragma unroll
      for (int n = 0; n < 4; ++n){
        int row = wn*64 + n*16 + r16;
        int ch = (t*4 + g4) ^ (r16 & 7);
        bfr[n] = *(const bf16x8*)&lB[row*64 + ch*8];
      }
#pragma unroll
      for (int m = 0; m < 4; ++m)
#pragma unroll
        for (int n = 0; n < 4; ++n)
          acc[m][n] = __builtin_amdgcn_mfma_f32_16x16x32_bf16(af[m], bfr[n], acc[m][n], 0, 0, 0);
    }
    __syncthreads();
  }
#pragma unroll
  for (int m = 0; m < 4; ++m){
#pragma unroll
    for (int n = 0; n < 4; ++n){
#pragma unroll
      for (int r = 0; r < 4; ++r){
        const int grow = m0 + wm*64 + m*16 + g4*4 + r;
        const int gcol = n0 + wn*64 + n*16 + r16;
        const float v = acc[m][n][r];
        if constexpr (MODE == 0){
          const float part = __shfl_xor(v, 1);   // RoPE partner (d^1)
          const int b = grow >> 11, nn = grow & (N_-1);
          const int s3 = gcol >> 10, hh = (gcol >> 6) & 15, d = gcol & 63;
          const size_t hb = (size_t)(b*H_ + hh);
          if (s3 == 2){
            vt[(hb*64 + d)*N_ + nn] = f2bf(v);
          } else {
            const int pidx = (b*N_ + nn)*32 + (d >> 1);
            const float c = cosT[pidx], sn = sinT[pidx];
            const float rot = (d & 1) ? (v*c + part*sn) : (v*c - part*sn);
            const u16 val = f2bf(rot);
            if (s3 == 0) qo[(hb*N_ + nn)*64 + d] = val;
            else         ko[(hb*N_ + nn)*64 + d] = val;
          }
        } else {
          outf[(size_t)grow*Nc + gcol] = v;
        }
      }
    }
  }
}

// ---------------- fused attention (swapped-QK^T, fixed-max softcap softmax) ----------------
#define PST 80   // P LDS row stride in elements (160B)
__global__ __launch_bounds__(256) void k_attn(
    const u16* __restrict__ qb, const u16* __restrict__ kb, const u16* __restrict__ vt,
    const int* __restrict__ mods, u16* __restrict__ xo)
{
  __shared__ u16 lK[64*64];
  __shared__ u16 lV[64*64];
  __shared__ u16 lP[4*16*PST];
  const int tid = threadIdx.x, wid = tid >> 6, lane = tid & 63;
  // XCD pinning: all 16 q-blocks of one bh on one XCD (xcd = bh&7)
  const int id = blockIdx.x;          // 0..511
  const int xcd = id & 7, slot = id >> 3;
  const int bh = xcd + 8*(slot & 3);
  const int qp = slot >> 2;           // 0..15
  const int b = bh >> 4, h = bh & 15;
  const int r16 = lane & 15, g4 = lane >> 4;
  const int srow = lane >> 3, sch = lane & 7;
  int moff[4], mend[4];
#pragma unroll
  for (int m = 0; m < 4; ++m){
    moff[m] = mods[(b*4+m)*3+1];
    mend[m] = moff[m] + mods[(b*4+m)*3+2];
  }
  const u16* kbase = kb + (size_t)bh*N_*64;
  const u16* vbase = vt + (size_t)bh*64*N_;
  u16* lPw = &lP[wid*16*PST];

  for (int pass = 0; pass < 2; ++pass){
    const int qt = pass ? (31 - qp) : qp;   // triangle pairing
    const int q0 = qt*64 + wid*16;
    const int i  = q0 + r16;                // this lane's q-row
    const int imax = qt*64 + 63;
    // modality threshold for this q-row: keep(j) <=> j <= i  ||  j < jmax
    int jmax = 0;
#pragma unroll
    for (int m = 0; m < 4; ++m)
      if (i >= moff[m]) jmax = max(jmax, mend[m]);
    const u16* qrow = qb + ((size_t)bh*N_ + q0 + r16)*64;
    const bf16x8 aq0 = *(const bf16x8*)&qrow[g4*8];
    const bf16x8 aq1 = *(const bf16x8*)&qrow[32 + g4*8];
    float lsum = 0.f;
    f32x4 o[4] = {};

    for (int kt = 0; kt < N_/64; ++kt){
      bool proc = (kt*64 <= imax);
      if (!proc){
#pragma unroll
        for (int m = 0; m < 4; ++m)
          if (imax >= moff[m] && kt*64 < mend[m]) proc = true;
      }
      if (!proc) continue;             // block-uniform skip
      __syncthreads();                 // previous-iter readers done
#pragma unroll
      for (int ld = 0; ld < 2; ++ld){
        int reg = wid*2 + ld;
        int row = reg*8 + srow;
        int gch = sch ^ srow;
        GLL16(kbase + (size_t)(kt*64 + row)*64 + gch*8, &lK[reg*512]);
        GLL16(vbase + (size_t)row*N_ + kt*64 + gch*8,   &lV[reg*512]);
      }
      __syncthreads();
      // S^T = K @ Q^T : lane holds q = q0+r16, k_local = cb*16 + g4*4 + r
      f32x4 s[4] = {};
#pragma unroll
      for (int cb = 0; cb < 4; ++cb){
#pragma unroll
        for (int t = 0; t < 2; ++t){
          int row = cb*16 + r16;
          int ch = (t*4 + g4) ^ (row & 7);
          bf16x8 bk = *(const bf16x8*)&lK[row*64 + ch*8];
          s[cb] = __builtin_amdgcn_mfma_f32_16x16x32_bf16(bk, t ? aq1 : aq0, s[cb], 0, 0, 0);
        }
      }
      const int thr = max(i, jmax - 1) - kt*64;        // keep <=> k_local <= thr
      const bool nomask = (kt*64 + 63 <= q0);          // wave-uniform interior tile
      // softcap -> p = exp(50*tanh(s*0.125/50)), mask, pack to LDS
#pragma unroll
      for (int cb = 0; cb < 4; ++cb){
        float p[4];
#pragma unroll
        for (int r = 0; r < 4; ++r){
          const float e = EXP2F(s[cb][r] * 0.0072134752f);        // 2^(s*0.005*log2e)
          const float w = RCPF(e + 1.0f);
          p[r] = EXP2F(fmaf(w, -144.2695041f, 72.13475205f));     // exp(50-100w)
        }
        if (!nomask){
#pragma unroll
          for (int r = 0; r < 4; ++r)
            p[r] = (cb*16 + g4*4 + r <= thr) ? p[r] : 0.0f;
        }
        lsum += (p[0] + p[1]) + (p[2] + p[3]);
        uint32_t w01, w23;
        asm("v_cvt_pk_bf16_f32 %0, %1, %2" : "=v"(w01) : "v"(p[0]), "v"(p[1]));
        asm("v_cvt_pk_bf16_f32 %0, %1, %2" : "=v"(w23) : "v"(p[2]), "v"(p[3]));
        *reinterpret_cast<uint2*>(&lPw[r16*PST + cb*16 + g4*4]) = make_uint2(w01, w23);
      }
      asm volatile("s_waitcnt lgkmcnt(0)" ::: "memory");
      __builtin_amdgcn_sched_barrier(0);
      const bf16x8 ap0 = *(const bf16x8*)&lPw[r16*PST + g4*8];
      const bf16x8 ap1 = *(const bf16x8*)&lPw[r16*PST + 32 + g4*8];
#pragma unroll
      for (int cb = 0; cb < 4; ++cb){
#pragma unroll
        for (int t = 0; t < 2; ++t){
          int d = cb*16 + r16;
          int ch = (t*4 + g4) ^ (d & 7);
          bf16x8 bv = *(const bf16x8*)&lV[d*64 + ch*8];
          o[cb] = __builtin_amdgcn_mfma_f32_16x16x32_bf16(t ? ap1 : ap0, bv, o[cb], 0, 0, 0);
        }
      }
    }
    // reduce row-sums across the 4 k-lane-groups, then normalize + store
    lsum += __shfl_xor(lsum, 16);
    lsum += __shfl_xor(lsum, 32);     // lanes with same r16 now hold full sum for q=q0+r16
#pragma unroll
    for (int r = 0; r < 4; ++r){
      const float linv = RCPF(__shfl(lsum, g4*4 + r));
      const int iq = q0 + g4*4 + r;
#pragma unroll
      for (int cb = 0; cb < 4; ++cb)
        xo[(size_t)(b*N_ + iq)*DIM_ + h*64 + cb*16 + r16] = f2bf(o[cb][r]*linv);
    }
  }
}

extern "C" void kernel_launch(void* const* d_in, const int* in_sizes, int n_in,
                              void* d_out, int out_size, void* d_ws, size_t ws_size,
                              hipStream_t stream){
  const float* x     = (const float*)d_in[0];
  const int*   mods  = (const int*)d_in[1];
  const float* gamma = (const float*)d_in[2];
  const float* wqkv  = (const float*)d_in[3];
  const float* wout  = (const float*)d_in[4];
  float* outp = (float*)d_out;

  char* p = (char*)d_ws;
  auto alloc = [&](size_t bytes) -> char* {
    char* r = p; p += (bytes + 255) & ~(size_t)255; return r;
  };
  float* pos   = (float*)alloc((size_t)B_*N_*4);
  float* cosT  = (float*)alloc((size_t)B_*N_*32*4);
  float* sinT  = (float*)alloc((size_t)B_*N_*32*4);
  u16* wqkvT   = (u16*)alloc((size_t)NH3*DIM_*2);
  u16* woutT   = (u16*)alloc((size_t)DIM_*DIM_*2);
  u16* xn      = (u16*)alloc((size_t)ROWS*DIM_*2);
  u16* qbb     = (u16*)alloc((size_t)B_*H_*N_*64*2);
  u16* kbb     = (u16*)alloc((size_t)B_*H_*N_*64*2);
  u16* vtb     = (u16*)alloc((size_t)B_*H_*N_*64*2);
  u16* xo      = (u16*)alloc((size_t)ROWS*DIM_*2);

  k_pos<<<B_, 64, 0, stream>>>(mods, pos);
  k_ropetab<<<(B_*N_*32 + 255)/256, 256, 0, stream>>>(pos, cosT, sinT);
  k_transpose<<<dim3(NH3/32, DIM_/32), 256, 0, stream>>>(wqkv, wqkvT, DIM_, NH3);
  k_transpose<<<dim3(DIM_/32, DIM_/32), 256, 0, stream>>>(wout, woutT, DIM_, DIM_);
  k_rmsnorm<<<ROWS, 256, 0, stream>>>(x, gamma, xn);
  k_gemm<0><<<dim3(ROWS/128, NH3/128), 256, 0, stream>>>(xn, wqkvT, DIM_, NH3, nullptr, cosT, sinT, qbb, kbb, vtb);
  k_attn<<<512, 256, 0, stream>>>(qbb, kbb, vtb, mods, xo);
  k_gemm<1><<<dim3(ROWS/128, DIM_/128), 256, 0, stream>>>(xo, woutT, DIM_, DIM_, outp, nullptr, nullptr, nullptr, nullptr, nullptr);
}

// Round 4
// 155.365 us; speedup vs baseline: 1.7086x; 1.0945x over previous
//
#include <hip/hip_runtime.h>
#include <hip/hip_bf16.h>
#include <stdint.h>

#define B_ 2
#define N_ 2048
#define H_ 16
#define DIM_ 1024
#define NH3 3072
#define ROWS (B_*N_)   // 4096

typedef __attribute__((ext_vector_type(8))) short bf16x8;
typedef __attribute__((ext_vector_type(4))) float f32x4;
typedef unsigned short u16;

__device__ __forceinline__ u16 f2bf(float f){
  union { float f; uint32_t u; } v; v.f = f;
  return (u16)((v.u + 0x7fffu + ((v.u >> 16) & 1u)) >> 16);
}

#if __has_builtin(__builtin_amdgcn_exp2f)
#define EXP2F(x) __builtin_amdgcn_exp2f(x)
#else
#define EXP2F(x) __expf((x) * 0.6931471805599453f)
#endif
#if __has_builtin(__builtin_amdgcn_rcpf)
#define RCPF(x) __builtin_amdgcn_rcpf(x)
#else
#define RCPF(x) (1.0f / (x))
#endif

#define GLL16(g, l) __builtin_amdgcn_global_load_lds( \
    (const __attribute__((address_space(1))) void*)(g), \
    (__attribute__((address_space(3))) void*)(l), 16, 0, 0)

// ---------------- positions ----------------
__global__ void k_pos(const int* __restrict__ mods, float* __restrict__ pos){
  const int b = blockIdx.x;
  const int lane = threadIdx.x;
  int off[4], len[4];
#pragma unroll
  for (int m = 0; m < 4; ++m){
    off[m] = mods[(b*4 + m)*3 + 1];
    len[m] = mods[(b*4 + m)*3 + 2];
  }
  int run = 0;
  for (int c = 0; c < N_/64; ++c){
    int n = c*64 + lane;
    int v = 0;
#pragma unroll
    for (int m = 0; m < 4; ++m)
      if (n >= off[m] + 1 && n < off[m] + len[m]) v = 1;
    int s = v;
#pragma unroll
    for (int d = 1; d < 64; d <<= 1){
      int t = __shfl_up(s, d);
      if (lane >= d) s += t;
    }
    pos[b*N_ + n] = (float)(n - (run + s));
    run += __shfl(s, 63);
  }
}

// ---------------- RoPE cos/sin tables ----------------
__global__ void k_ropetab(const float* __restrict__ pos, float* __restrict__ cosT, float* __restrict__ sinT){
  int t = blockIdx.x*256 + threadIdx.x;
  if (t >= B_*N_*32) return;
  int f = t & 31, bn = t >> 5;
  float inv = powf(10000.0f, -(float)(2*f) / 64.0f);
  float ang = pos[bn] * inv;
  float s, c;
  sincosf(ang, &s, &c);
  cosT[t] = c; sinT[t] = s;
}

// ---------------- fp32 -> bf16 transpose (weights) ----------------
__global__ void k_transpose(const float* __restrict__ src, u16* __restrict__ dst, int R, int C){
  __shared__ float tile[32][33];
  int tx = threadIdx.x & 31, ty = threadIdx.x >> 5; // 32x8
  int bc = blockIdx.x * 32, br = blockIdx.y * 32;
#pragma unroll
  for (int i = 0; i < 32; i += 8)
    tile[ty + i][tx] = src[(size_t)(br + ty + i)*C + bc + tx];
  __syncthreads();
#pragma unroll
  for (int i = 0; i < 32; i += 8)
    dst[(size_t)(bc + ty + i)*R + br + tx] = f2bf(tile[tx][ty + i]);
}

// ---------------- row-norm (x / ||x|| * sqrt(d) * (gamma+1)) ----------------
__global__ __launch_bounds__(256) void k_rmsnorm(const float* __restrict__ x, const float* __restrict__ gamma, u16* __restrict__ xn){
  int row = blockIdx.x, t = threadIdx.x;
  const float4 xv = ((const float4*)(x + (size_t)row*DIM_))[t];
  float ss = xv.x*xv.x + xv.y*xv.y + xv.z*xv.z + xv.w*xv.w;
#pragma unroll
  for (int d = 1; d < 64; d <<= 1) ss += __shfl_xor(ss, d);
  __shared__ float red[4];
  if ((t & 63) == 0) red[t >> 6] = ss;
  __syncthreads();
  float tot = red[0] + red[1] + red[2] + red[3];
  float scl = 32.0f / fmaxf(sqrtf(tot), 1e-12f);   // sqrt(1024)=32
  const float4 gv = ((const float4*)gamma)[t];
  ushort4 o;
  o.x = f2bf(xv.x * scl * (gv.x + 1.0f));
  o.y = f2bf(xv.y * scl * (gv.y + 1.0f));
  o.z = f2bf(xv.z * scl * (gv.z + 1.0f));
  o.w = f2bf(xv.w * scl * (gv.w + 1.0f));
  ((ushort4*)(xn + (size_t)row*DIM_))[t] = o;
}

// ---------------- BMx128 bf16 MFMA GEMM: C = A @ Bt^T ----------------
// MODE 0 (BM=128): epilogue applies RoPE -> q/k bf16 [B,H,N,64], v^T bf16 [B,H,64,N]
// MODE 1 (BM=64):  plain fp32 store to outf [M][Nc]
template<int MODE, int BM>
__global__ __launch_bounds__(256) void k_gemm(
    const u16* __restrict__ A, const u16* __restrict__ Bt,
    int K, int Nc,
    float* __restrict__ outf,
    const float* __restrict__ cosT, const float* __restrict__ sinT,
    u16* __restrict__ qo, u16* __restrict__ ko, u16* __restrict__ vt)
{
  constexpr int MR = BM/32;        // m-fragments per wave
  constexpr int RA = BM/8;         // A staging regions
  constexpr int CNT = (RA + 16)/4; // staging regions per wave
  __shared__ u16 lA[BM*64];
  __shared__ u16 lB[128*64];
  const int tid = threadIdx.x;
  const int wid = tid >> 6, lane = tid & 63;
  // XCD-aware bijective chunked remap (nwg % 8 == 0 for both launches)
  const int nx = gridDim.x;
  const int orig = blockIdx.y * nx + blockIdx.x;
  const int qq = (nx * gridDim.y) >> 3;
  const int wgid = (orig & 7) * qq + (orig >> 3);
  const int m0 = (wgid % nx) * BM, n0 = (wgid / nx) * 128;
  const int wm = wid >> 1, wn = wid & 1;
  const int srow = lane >> 3, sch = lane & 7;
  const int r16 = lane & 15, g4 = lane >> 4;
  f32x4 acc[MR][4] = {};
  const int ksteps = K >> 6;
  for (int kt = 0; kt < ksteps; ++kt){
    const int kb = kt*64;
    const int gch = sch ^ srow;          // pre-swizzled global source chunk
#pragma unroll
    for (int i = 0; i < CNT; ++i){
      const int reg = wid*CNT + i;
      if (reg < RA){
        const int row = reg*8 + srow;
        GLL16(A + (size_t)(m0 + row)*K + kb + gch*8, &lA[reg*512]);
      } else {
        const int r2 = reg - RA;
        const int row = r2*8 + srow;
        GLL16(Bt + (size_t)(n0 + row)*K + kb + gch*8, &lB[r2*512]);
      }
    }
    __syncthreads();
#pragma unroll
    for (int t = 0; t < 2; ++t){
      bf16x8 af[MR], bfr[4];
#pragma unroll
      for (int m = 0; m < MR; ++m){
        int row = wm*(BM/2) + m*16 + r16;
        int ch = (t*4 + g4) ^ (r16 & 7);
        af[m] = *(const bf16x8*)&lA[row*64 + ch*8];
      }
#pragma unroll
      for (int n = 0; n < 4; ++n){
        int row = wn*64 + n*16 + r16;
        int ch = (t*4 + g4) ^ (r16 & 7);
        bfr[n] = *(const bf16x8*)&lB[row*64 + ch*8];
      }
#pragma unroll
      for (int m = 0; m < MR; ++m)
#pragma unroll
        for (int n = 0; n < 4; ++n)
          acc[m][n] = __builtin_amdgcn_mfma_f32_16x16x32_bf16(af[m], bfr[n], acc[m][n], 0, 0, 0);
    }
    __syncthreads();
  }
#pragma unroll
  for (int m = 0; m < MR; ++m){
#pragma unroll
    for (int n = 0; n < 4; ++n){
#pragma unroll
      for (int r = 0; r < 4; ++r){
        const int grow = m0 + wm*(BM/2) + m*16 + g4*4 + r;
        const int gcol = n0 + wn*64 + n*16 + r16;
        const float v = acc[m][n][r];
        if constexpr (MODE == 0){
          const float part = __shfl_xor(v, 1);   // RoPE partner (d^1)
          const int b = grow >> 11, nn = grow & (N_-1);
          const int s3 = gcol >> 10, hh = (gcol >> 6) & 15, d = gcol & 63;
          const size_t hb = (size_t)(b*H_ + hh);
          if (s3 == 2){
            vt[(hb*64 + d)*N_ + nn] = f2bf(v);
          } else {
            const int pidx = (b*N_ + nn)*32 + (d >> 1);
            const float c = cosT[pidx], sn = sinT[pidx];
            const float rot = (d & 1) ? (v*c + part*sn) : (v*c - part*sn);
            const u16 val = f2bf(rot);
            if (s3 == 0) qo[(hb*N_ + nn)*64 + d] = val;
            else         ko[(hb*N_ + nn)*64 + d] = val;
          }
        } else {
          outf[(size_t)grow*Nc + gcol] = v;
        }
      }
    }
  }
}

// ---------------- fused attention (swapped-QK^T, poly softcap, fixed-max) ----------------
#define PST 72   // P LDS row stride in elements (144B = odd*16B -> conflict-free)
__global__ __launch_bounds__(256) void k_attn(
    const u16* __restrict__ qb, const u16* __restrict__ kb, const u16* __restrict__ vt,
    const int* __restrict__ mods, u16* __restrict__ xo)
{
  __shared__ u16 lK[64*64];
  __shared__ u16 lV[64*64];
  __shared__ u16 lP[4*16*PST];
  const int tid = threadIdx.x, wid = tid >> 6, lane = tid & 63;
  // XCD pinning + per-CU load balancing:
  // xcd = id&7; slot = id>>3. CU c on an XCD receives slots {c, c+32, c+64, c+96}:
  // same bh (slot&3 = c&3), qslots {a, a+8, a+16, a+24} (a=c>>2) -> map to
  // qt {a, 15-a, 16+a, 31-a}: per-CU causal tile total == 62 for every CU.
  const int id = blockIdx.x;          // 0..1023
  const int xcd = id & 7, slot = id >> 3;
  const int bh = xcd + 8*(slot & 3);
  const int qslot = slot >> 2;        // 0..31
  const int aa = qslot & 7, grp = qslot >> 3;
  const int qt = (grp == 0) ? aa : (grp == 1) ? (15 - aa) : (grp == 2) ? (16 + aa) : (31 - aa);
  const int b = bh >> 4, h = bh & 15;
  const int r16 = lane & 15, g4 = lane >> 4;
  const int srow = lane >> 3, sch = lane & 7;
  int moff[4], mend[4];
#pragma unroll
  for (int m = 0; m < 4; ++m){
    moff[m] = mods[(b*4+m)*3+1];
    mend[m] = moff[m] + mods[(b*4+m)*3+2];
  }
  const u16* kbase = kb + (size_t)bh*N_*64;
  const u16* vbase = vt + (size_t)bh*64*N_;
  u16* lPw = &lP[wid*16*PST];

  const int q0 = qt*64 + wid*16;
  const int i  = q0 + r16;                // this lane's q-row
  const int imax = qt*64 + 63;
  int jmax = 0;
#pragma unroll
  for (int m = 0; m < 4; ++m)
    if (i >= moff[m]) jmax = max(jmax, mend[m]);
  const u16* qrow = qb + ((size_t)bh*N_ + q0 + r16)*64;
  const bf16x8 aq0 = *(const bf16x8*)&qrow[g4*8];
  const bf16x8 aq1 = *(const bf16x8*)&qrow[32 + g4*8];
  float lsum = 0.f;
  f32x4 o[4] = {};

  // 50*tanh(v/50)*log2(e) odd series coefficients (u = v^2)
  const float C1 = 1.4426950408889634f;
  const float C3 = -1.9235933878519512e-04f;
  const float C5 = 3.0777494205631218e-08f;
  const float C7 = -4.9826551922463556e-12f;

  for (int kt = 0; kt < N_/64; ++kt){
    bool proc = (kt*64 <= imax);
    if (!proc){
#pragma unroll
      for (int m = 0; m < 4; ++m)
        if (imax >= moff[m] && kt*64 < mend[m]) proc = true;
    }
    if (!proc) continue;             // block-uniform skip
    __syncthreads();                 // previous-iter readers done
#pragma unroll
    for (int ld = 0; ld < 2; ++ld){
      int reg = wid*2 + ld;
      int row = reg*8 + srow;
      int gch = sch ^ srow;
      GLL16(kbase + (size_t)(kt*64 + row)*64 + gch*8, &lK[reg*512]);
      GLL16(vbase + (size_t)row*N_ + kt*64 + gch*8,   &lV[reg*512]);
    }
    __syncthreads();
    // S^T = K @ Q^T : lane holds q = q0+r16, k_local = cb*16 + g4*4 + r
    f32x4 s[4] = {};
    __builtin_amdgcn_s_setprio(1);
#pragma unroll
    for (int cb = 0; cb < 4; ++cb){
#pragma unroll
      for (int t = 0; t < 2; ++t){
        int row = cb*16 + r16;
        int ch = (t*4 + g4) ^ (row & 7);
        bf16x8 bk = *(const bf16x8*)&lK[row*64 + ch*8];
        s[cb] = __builtin_amdgcn_mfma_f32_16x16x32_bf16(bk, t ? aq1 : aq0, s[cb], 0, 0, 0);
      }
    }
    __builtin_amdgcn_s_setprio(0);
    const int thr = max(i, jmax - 1) - kt*64;        // keep <=> k_local <= thr
    const bool nomask = (kt*64 + 63 <= q0);          // wave-uniform interior tile
    // p = exp(50*tanh(s*0.125/50)) via odd polynomial exponent (1 trans/elem)
#pragma unroll
    for (int cb = 0; cb < 4; ++cb){
      float p[4];
#pragma unroll
      for (int r = 0; r < 4; ++r){
        const float v = s[cb][r] * 0.125f;
        const float u = v*v;
        const float g2 = v*(C1 + u*(C3 + u*(C5 + u*C7)));
        p[r] = EXP2F(g2);
      }
      if (!nomask){
#pragma unroll
        for (int r = 0; r < 4; ++r)
          p[r] = (cb*16 + g4*4 + r <= thr) ? p[r] : 0.0f;
      }
      lsum += (p[0] + p[1]) + (p[2] + p[3]);
      uint32_t w01, w23;
      asm("v_cvt_pk_bf16_f32 %0, %1, %2" : "=v"(w01) : "v"(p[0]), "v"(p[1]));
      asm("v_cvt_pk_bf16_f32 %0, %1, %2" : "=v"(w23) : "v"(p[2]), "v"(p[3]));
      *reinterpret_cast<uint2*>(&lPw[r16*PST + cb*16 + g4*4]) = make_uint2(w01, w23);
    }
    asm volatile("s_waitcnt lgkmcnt(0)" ::: "memory");
    __builtin_amdgcn_sched_barrier(0);
    const bf16x8 ap0 = *(const bf16x8*)&lPw[r16*PST + g4*8];
    const bf16x8 ap1 = *(const bf16x8*)&lPw[r16*PST + 32 + g4*8];
    __builtin_amdgcn_s_setprio(1);
#pragma unroll
    for (int cb = 0; cb < 4; ++cb){
#pragma unroll
      for (int t = 0; t < 2; ++t){
        int d = cb*16 + r16;
        int ch = (t*4 + g4) ^ (d & 7);
        bf16x8 bv = *(const bf16x8*)&lV[d*64 + ch*8];
        o[cb] = __builtin_amdgcn_mfma_f32_16x16x32_bf16(t ? ap1 : ap0, bv, o[cb], 0, 0, 0);
      }
    }
    __builtin_amdgcn_s_setprio(0);
  }
  // reduce row-sums across the 4 k-lane-groups, then normalize + store
  lsum += __shfl_xor(lsum, 16);
  lsum += __shfl_xor(lsum, 32);     // all replicas hold full sum for q=q0+r16
#pragma unroll
  for (int r = 0; r < 4; ++r){
    const float linv = RCPF(__shfl(lsum, g4*4 + r));
    const int iq = q0 + g4*4 + r;
#pragma unroll
    for (int cb = 0; cb < 4; ++cb)
      xo[(size_t)(b*N_ + iq)*DIM_ + h*64 + cb*16 + r16] = f2bf(o[cb][r]*linv);
  }
}

extern "C" void kernel_launch(void* const* d_in, const int* in_sizes, int n_in,
                              void* d_out, int out_size, void* d_ws, size_t ws_size,
                              hipStream_t stream){
  const float* x     = (const float*)d_in[0];
  const int*   mods  = (const int*)d_in[1];
  const float* gamma = (const float*)d_in[2];
  const float* wqkv  = (const float*)d_in[3];
  const float* wout  = (const float*)d_in[4];
  float* outp = (float*)d_out;

  char* p = (char*)d_ws;
  auto alloc = [&](size_t bytes) -> char* {
    char* r = p; p += (bytes + 255) & ~(size_t)255; return r;
  };
  float* pos   = (float*)alloc((size_t)B_*N_*4);
  float* cosT  = (float*)alloc((size_t)B_*N_*32*4);
  float* sinT  = (float*)alloc((size_t)B_*N_*32*4);
  u16* wqkvT   = (u16*)alloc((size_t)NH3*DIM_*2);
  u16* woutT   = (u16*)alloc((size_t)DIM_*DIM_*2);
  u16* xn      = (u16*)alloc((size_t)ROWS*DIM_*2);
  u16* qbb     = (u16*)alloc((size_t)B_*H_*N_*64*2);
  u16* kbb     = (u16*)alloc((size_t)B_*H_*N_*64*2);
  u16* vtb     = (u16*)alloc((size_t)B_*H_*N_*64*2);
  u16* xo      = (u16*)alloc((size_t)ROWS*DIM_*2);

  k_pos<<<B_, 64, 0, stream>>>(mods, pos);
  k_ropetab<<<(B_*N_*32 + 255)/256, 256, 0, stream>>>(pos, cosT, sinT);
  k_transpose<<<dim3(NH3/32, DIM_/32), 256, 0, stream>>>(wqkv, wqkvT, DIM_, NH3);
  k_transpose<<<dim3(DIM_/32, DIM_/32), 256, 0, stream>>>(wout, woutT, DIM_, DIM_);
  k_rmsnorm<<<ROWS, 256, 0, stream>>>(x, gamma, xn);
  k_gemm<0,128><<<dim3(ROWS/128, NH3/128), 256, 0, stream>>>(xn, wqkvT, DIM_, NH3, nullptr, cosT, sinT, qbb, kbb, vtb);
  k_attn<<<1024, 256, 0, stream>>>(qbb, kbb, vtb, mods, xo);
  k_gemm<1,64><<<dim3(ROWS/64, DIM_/128), 256, 0, stream>>>(xo, woutT, DIM_, DIM_, outp, nullptr, nullptr, nullptr, nullptr, nullptr);
}